// Round 1
// baseline (622.950 us; speedup 1.0000x reference)
//
#include <hip/hip_runtime.h>
#include <hip/hip_bf16.h>
#include <stdint.h>
#include <stddef.h>

#define NN 8192
#define DD 128
#define TILE 128

typedef __attribute__((ext_vector_type(8))) short bf16x8;
typedef __attribute__((ext_vector_type(4))) float f32x4;

// async global->LDS, 16B per lane. LDS dest must be wave-uniform base + lane*16.
#define GLOBAL_LOAD_LDS16(gptr, lptr)                                               \
  __builtin_amdgcn_global_load_lds(                                                 \
      (const __attribute__((address_space(1))) unsigned int*)(gptr),                \
      (__attribute__((address_space(3))) unsigned int*)(lptr), 16, 0, 0)

// ---------------------------------------------------------------------------
// Kernel 1: row-normalize features (fp32) and cast to bf16.
// One wave per row: 64 lanes x 2 floats = 128 elements.
// ---------------------------------------------------------------------------
__global__ __launch_bounds__(256) void normalize_kernel(
    const float* __restrict__ f, __hip_bfloat16* __restrict__ fn) {
  const int wave = threadIdx.x >> 6;
  const int lane = threadIdx.x & 63;
  const int row = blockIdx.x * 4 + wave;
  const float2 v = ((const float2*)(f + (size_t)row * DD))[lane];
  float ss = v.x * v.x + v.y * v.y;
#pragma unroll
  for (int m = 1; m < 64; m <<= 1) ss += __shfl_xor(ss, m, 64);
  const float norm = fmaxf(sqrtf(ss), 1e-8f);
  const float inv = 1.0f / norm;
  __hip_bfloat162 o;
  o.x = __float2bfloat16(v.x * inv);
  o.y = __float2bfloat16(v.y * inv);
  ((__hip_bfloat162*)(fn + (size_t)row * DD))[lane] = o;
}

// ---------------------------------------------------------------------------
// Kernel 2: fused sim-tile GEMM (bf16 MFMA) + exp + masked row-sum.
// Block = 256 threads = 2x2 waves, each wave computes 64x64 of a 128x128 tile.
// K = D = 128 staged once into LDS (no K-loop staging needed).
// ---------------------------------------------------------------------------
__global__ __launch_bounds__(256, 2) void ssnt_main(
    const __hip_bfloat16* __restrict__ fn,
    const int* __restrict__ pmask,
    const int* __restrict__ nmask,
    float* __restrict__ pos, float* __restrict__ neg, float* __restrict__ cnt) {
  __shared__ __hip_bfloat16 ldsA[TILE * DD];  // 32 KB
  __shared__ __hip_bfloat16 ldsB[TILE * DD];  // 32 KB

  const int tid = threadIdx.x;
  const int lane = tid & 63;
  const int quad = lane >> 4;
  const int l16 = lane & 15;
  const int wx = (tid >> 6) & 1;
  const int wy = tid >> 7;

  const int I0 = blockIdx.y * TILE;
  const int J0 = blockIdx.x * TILE;

  // Stage A rows [I0,I0+128) and B rows [J0,J0+128): each is a contiguous
  // 32 KB block of row-major [8192][128] bf16.
  {
    const char* gA = (const char*)(fn + (size_t)I0 * DD);
    const char* gB = (const char*)(fn + (size_t)J0 * DD);
    char* lA = (char*)ldsA;
    char* lB = (char*)ldsB;
#pragma unroll
    for (int it = 0; it < 8; ++it) {
      const int off = (it * 256 + tid) * 16;  // wave-uniform base + lane*16
      GLOBAL_LOAD_LDS16(gA + off, lA + off);
      GLOBAL_LOAD_LDS16(gB + off, lB + off);
    }
  }
  __syncthreads();

  f32x4 acc[4][4] = {};
#pragma unroll
  for (int kt = 0; kt < 4; ++kt) {
    const int ko = kt * 32 + quad * 8;
    bf16x8 aF[4], bF[4];
#pragma unroll
    for (int mt = 0; mt < 4; ++mt)
      aF[mt] = *(const bf16x8*)(ldsA + (wy * 64 + mt * 16 + l16) * DD + ko);
#pragma unroll
    for (int nt = 0; nt < 4; ++nt)
      bF[nt] = *(const bf16x8*)(ldsB + (wx * 64 + nt * 16 + l16) * DD + ko);
#pragma unroll
    for (int mt = 0; mt < 4; ++mt)
#pragma unroll
      for (int nt = 0; nt < 4; ++nt)
        acc[mt][nt] = __builtin_amdgcn_mfma_f32_16x16x32_bf16(
            aF[mt], bF[nt], acc[mt][nt], 0, 0, 0);
  }

  // Epilogue: exp(sim/T), mask, per-row accumulate.
  // C/D layout: col = lane&15, row = quad*4 + reg (within 16x16 tile).
  const float tinv = 1.0f / 0.07f;
  const int rowBase = I0 + wy * 64;
  const int colBase = J0 + wx * 64;
#pragma unroll
  for (int mt = 0; mt < 4; ++mt) {
    float pA[4] = {0.f, 0.f, 0.f, 0.f};
    float qA[4] = {0.f, 0.f, 0.f, 0.f};
    float cA[4] = {0.f, 0.f, 0.f, 0.f};
#pragma unroll
    for (int nt = 0; nt < 4; ++nt) {
      const int gcol = colBase + nt * 16 + l16;
#pragma unroll
      for (int r = 0; r < 4; ++r) {
        const int grow = rowBase + mt * 16 + quad * 4 + r;
        const float e = __expf(acc[mt][nt][r] * tinv);
        const size_t idx = (size_t)grow * NN + gcol;
        float pm = (float)pmask[idx];
        float nm = (float)nmask[idx];
        if (grow == gcol) { pm = 0.f; nm = 0.f; }  // zero self-contrast
        pA[r] = fmaf(e, pm, pA[r]);
        qA[r] = fmaf(e, nm, qA[r]);
        cA[r] += pm;
      }
    }
    // reduce across the 16 col-lanes of each quad group, then atomic per row
#pragma unroll
    for (int r = 0; r < 4; ++r) {
      float p = pA[r], q = qA[r], c = cA[r];
#pragma unroll
      for (int m = 1; m < 16; m <<= 1) {
        p += __shfl_xor(p, m, 64);
        q += __shfl_xor(q, m, 64);
        c += __shfl_xor(c, m, 64);
      }
      if (l16 == 0) {
        const int grow = rowBase + mt * 16 + quad * 4 + r;
        atomicAdd(&pos[grow], p);
        atomicAdd(&neg[grow], q);
        atomicAdd(&cnt[grow], c);
      }
    }
  }
}

// ---------------------------------------------------------------------------
// Kernel 3: loss = -mean(log(pos/(pos+neg)) / cnt)
// ---------------------------------------------------------------------------
__global__ __launch_bounds__(256) void finalize_kernel(
    const float* __restrict__ pos, const float* __restrict__ neg,
    const float* __restrict__ cnt, float* __restrict__ out) {
  float s = 0.f;
  for (int i = threadIdx.x; i < NN; i += 256) {
    const float p = pos[i];
    const float q = neg[i];
    s += logf(p / (p + q)) / cnt[i];
  }
#pragma unroll
  for (int m = 1; m < 64; m <<= 1) s += __shfl_xor(s, m, 64);
  __shared__ float wsum[4];
  if ((threadIdx.x & 63) == 0) wsum[threadIdx.x >> 6] = s;
  __syncthreads();
  if (threadIdx.x == 0) {
    out[0] = -(wsum[0] + wsum[1] + wsum[2] + wsum[3]) / (float)NN;
  }
}

extern "C" void kernel_launch(void* const* d_in, const int* in_sizes, int n_in,
                              void* d_out, int out_size, void* d_ws, size_t ws_size,
                              hipStream_t stream) {
  const float* features = (const float*)d_in[0];
  const int* pmask = (const int*)d_in[1];
  const int* nmask = (const int*)d_in[2];
  float* out = (float*)d_out;

  char* ws = (char*)d_ws;
  __hip_bfloat16* fn = (__hip_bfloat16*)ws;                     // 2 MB
  float* pos = (float*)(ws + (size_t)NN * DD * sizeof(__hip_bfloat16));
  float* neg = pos + NN;
  float* cnt = neg + NN;

  hipMemsetAsync(pos, 0, 3 * (size_t)NN * sizeof(float), stream);
  normalize_kernel<<<NN / 4, 256, 0, stream>>>(features, fn);
  ssnt_main<<<dim3(NN / TILE, NN / TILE), 256, 0, stream>>>(fn, pmask, nmask,
                                                            pos, neg, cnt);
  finalize_kernel<<<1, 256, 0, stream>>>(pos, neg, cnt, out);
}

// Round 2
// 566.222 us; speedup vs baseline: 1.1002x; 1.1002x over previous
//
#include <hip/hip_runtime.h>
#include <hip/hip_bf16.h>
#include <stdint.h>
#include <stddef.h>

#define NN 8192
#define DD 128

typedef __attribute__((ext_vector_type(8))) short bf16x8;
typedef __attribute__((ext_vector_type(4))) float f32x4;

// ---------------------------------------------------------------------------
// Kernel 1: row-normalize features (fp32) and cast to bf16.
// One wave per row: 64 lanes x 2 floats = 128 elements.
// ---------------------------------------------------------------------------
__global__ __launch_bounds__(256) void normalize_kernel(
    const float* __restrict__ f, __hip_bfloat16* __restrict__ fn) {
  const int wave = threadIdx.x >> 6;
  const int lane = threadIdx.x & 63;
  const int row = blockIdx.x * 4 + wave;
  const float2 v = ((const float2*)(f + (size_t)row * DD))[lane];
  float ss = v.x * v.x + v.y * v.y;
#pragma unroll
  for (int m = 1; m < 64; m <<= 1) ss += __shfl_xor(ss, m, 64);
  const float inv = 1.0f / fmaxf(sqrtf(ss), 1e-8f);
  __hip_bfloat162 o;
  o.x = __float2bfloat16(v.x * inv);
  o.y = __float2bfloat16(v.y * inv);
  ((__hip_bfloat162*)(fn + (size_t)row * DD))[lane] = o;
}

// ---------------------------------------------------------------------------
// Kernel 2: fused sim-tile GEMM (bf16 MFMA, operand-SWAPPED) + exp + masked
// row-sums. No LDS, no barriers: fn is 2 MB -> L2-resident, fragments load
// straight from global. Block = 256 = 2x2 waves, each wave owns 64x64 of a
// 128x128 tile.
//
// Operand swap: acc[mt][nt] = mfma(bF[nt], aF[mt], ...) puts
//   i = I0 + mt*16 + l16          (loss row, from aF as B-operand)
//   j = J0 + nt*16 + quad*4 + r   (loss col, from bF as A-operand)
// so one lane's 4 acc regs are 4 CONSECUTIVE j -> int4 mask loads, and the
// row-reduction is only across the 4 quads (2 shuffles).
// ---------------------------------------------------------------------------
__global__ __launch_bounds__(256, 4) void ssnt_main(
    const __hip_bfloat16* __restrict__ fn,
    const int* __restrict__ pmask,
    const int* __restrict__ nmask,
    float* __restrict__ pos, float* __restrict__ neg, float* __restrict__ cnt) {
  const int tid = threadIdx.x;
  const int lane = tid & 63;
  const int quad = lane >> 4;
  const int l16 = lane & 15;
  const int wx = (tid >> 6) & 1;
  const int wy = tid >> 7;

  const int I0 = blockIdx.y * 128 + wy * 64;  // loss-row base for this wave
  const int J0 = blockIdx.x * 128 + wx * 64;  // loss-col base for this wave

  f32x4 acc[4][4] = {};
#pragma unroll
  for (int kt = 0; kt < 4; ++kt) {
    const int ko = kt * 32 + quad * 8;
    bf16x8 aF[4], bF[4];
#pragma unroll
    for (int mt = 0; mt < 4; ++mt)
      aF[mt] = *(const bf16x8*)(fn + (size_t)(I0 + mt * 16 + l16) * DD + ko);
#pragma unroll
    for (int nt = 0; nt < 4; ++nt)
      bF[nt] = *(const bf16x8*)(fn + (size_t)(J0 + nt * 16 + l16) * DD + ko);
#pragma unroll
    for (int mt = 0; mt < 4; ++mt)
#pragma unroll
      for (int nt = 0; nt < 4; ++nt)
        acc[mt][nt] = __builtin_amdgcn_mfma_f32_16x16x32_bf16(
            bF[nt], aF[mt], acc[mt][nt], 0, 0, 0);  // SWAPPED
  }

  // exp(sim/T) in place (VALU-only; mask loads below are independent and can
  // be hoisted/overlapped by the scheduler)
  const float tinv = 1.0f / 0.07f;
#pragma unroll
  for (int mt = 0; mt < 4; ++mt)
#pragma unroll
    for (int nt = 0; nt < 4; ++nt)
#pragma unroll
      for (int r = 0; r < 4; ++r)
        acc[mt][nt][r] = __expf(acc[mt][nt][r] * tinv);

#pragma unroll
  for (int mt = 0; mt < 4; ++mt) {
    const int i = I0 + mt * 16 + l16;
    const size_t rowOff = (size_t)i * NN;
    float p = 0.f, q = 0.f, c = 0.f;
#pragma unroll
    for (int nt = 0; nt < 4; ++nt) {
      const int j0 = J0 + nt * 16 + quad * 4;
      const int4 pm4 = *(const int4*)(pmask + rowOff + j0);
      const int4 nm4 = *(const int4*)(nmask + rowOff + j0);
#pragma unroll
      for (int r = 0; r < 4; ++r) {
        int pm = (&pm4.x)[r];
        int nm = (&nm4.x)[r];
        if (i == j0 + r) { pm = 0; nm = 0; }  // zero self-contrast
        const float e = acc[mt][nt][r];
        p = fmaf(e, (float)pm, p);
        q = fmaf(e, (float)nm, q);
        c += (float)pm;
      }
    }
    // reduce across the 4 quads (same i for all quads at fixed l16)
    p += __shfl_xor(p, 16, 64);
    p += __shfl_xor(p, 32, 64);
    q += __shfl_xor(q, 16, 64);
    q += __shfl_xor(q, 32, 64);
    c += __shfl_xor(c, 16, 64);
    c += __shfl_xor(c, 32, 64);
    // one quad per output array -> 3 coalesced 16-lane atomic instructions
    if (quad == 0) atomicAdd(&pos[i], p);
    else if (quad == 1) atomicAdd(&neg[i], q);
    else if (quad == 2) atomicAdd(&cnt[i], c);
  }
}

// ---------------------------------------------------------------------------
// Kernel 3: loss = -mean(log(pos/(pos+neg)) / cnt)
// ---------------------------------------------------------------------------
__global__ __launch_bounds__(256) void finalize_kernel(
    const float* __restrict__ pos, const float* __restrict__ neg,
    const float* __restrict__ cnt, float* __restrict__ out) {
  float s = 0.f;
  for (int i = threadIdx.x; i < NN; i += 256) {
    const float p = pos[i];
    const float q = neg[i];
    s += logf(p / (p + q)) / cnt[i];
  }
#pragma unroll
  for (int m = 1; m < 64; m <<= 1) s += __shfl_xor(s, m, 64);
  __shared__ float wsum[4];
  if ((threadIdx.x & 63) == 0) wsum[threadIdx.x >> 6] = s;
  __syncthreads();
  if (threadIdx.x == 0) {
    out[0] = -(wsum[0] + wsum[1] + wsum[2] + wsum[3]) / (float)NN;
  }
}

extern "C" void kernel_launch(void* const* d_in, const int* in_sizes, int n_in,
                              void* d_out, int out_size, void* d_ws, size_t ws_size,
                              hipStream_t stream) {
  const float* features = (const float*)d_in[0];
  const int* pmask = (const int*)d_in[1];
  const int* nmask = (const int*)d_in[2];
  float* out = (float*)d_out;

  char* ws = (char*)d_ws;
  __hip_bfloat16* fn = (__hip_bfloat16*)ws;  // 2 MB
  float* pos = (float*)(ws + (size_t)NN * DD * sizeof(__hip_bfloat16));
  float* neg = pos + NN;
  float* cnt = neg + NN;

  hipMemsetAsync(pos, 0, 3 * (size_t)NN * sizeof(float), stream);
  normalize_kernel<<<NN / 4, 256, 0, stream>>>(features, fn);
  ssnt_main<<<dim3(NN / 128, NN / 128), 256, 0, stream>>>(fn, pmask, nmask,
                                                          pos, neg, cnt);
  finalize_kernel<<<1, 256, 0, stream>>>(pos, neg, cnt, out);
}

// Round 3
// 553.109 us; speedup vs baseline: 1.1263x; 1.0237x over previous
//
#include <hip/hip_runtime.h>
#include <hip/hip_bf16.h>
#include <stdint.h>
#include <stddef.h>

#define NN 8192
#define DD 128
#define PADW 136  // LDS row stride in bf16: 272 B, 16B-aligned, breaks 16-way conflicts

typedef __attribute__((ext_vector_type(8))) short bf16x8;
typedef __attribute__((ext_vector_type(4))) float f32x4;

static __device__ __forceinline__ unsigned short f2bf(float x) {
  __hip_bfloat16 h = __float2bfloat16(x);
  return *(unsigned short*)&h;
}

// ---------------------------------------------------------------------------
// Kernel 1: row-normalize features (fp32) and cast to bf16. One wave per row.
// ---------------------------------------------------------------------------
__global__ __launch_bounds__(256) void normalize_kernel(
    const float* __restrict__ f, __hip_bfloat16* __restrict__ fn) {
  const int wave = threadIdx.x >> 6;
  const int lane = threadIdx.x & 63;
  const int row = blockIdx.x * 4 + wave;
  const float2 v = ((const float2*)(f + (size_t)row * DD))[lane];
  float ss = v.x * v.x + v.y * v.y;
#pragma unroll
  for (int m = 1; m < 64; m <<= 1) ss += __shfl_xor(ss, m, 64);
  const float inv = 1.0f / fmaxf(sqrtf(ss), 1e-8f);
  __hip_bfloat162 o;
  o.x = __float2bfloat16(v.x * inv);
  o.y = __float2bfloat16(v.y * inv);
  ((__hip_bfloat162*)(fn + (size_t)row * DD))[lane] = o;
}

// ---------------------------------------------------------------------------
// Kernel 2: fused 128x128 sim-tile GEMM (bf16 MFMA, operand-swapped) + exp ->
// LDS (bf16) -> row-major masked accumulation with COALESCED mask reads.
//
// Phase 1: GEMM, fragments straight from L2 (fn is 2 MB).
//   swap: acc[mt][nt] = mfma(bF[nt], aF[mt]) =>
//     i = I0 + wy*64 + mt*16 + l16, j = J0 + wx*64 + nt*16 + quad*4 + r
// Phase 2: exp(sim/T) -> LDS bf16 sim[128][PADW], one ds_write_b64 per frag.
// Phase 3: rows handled row-major: 16 lanes x 8 cols each; mask loads are
//   512B-contiguous per row (streaming pattern), exp via ds_read_b128,
//   4-shuffle reduce, one atomic per row/array.
// ---------------------------------------------------------------------------
__global__ __launch_bounds__(256, 4) void ssnt_main(
    const __hip_bfloat16* __restrict__ fn,
    const int* __restrict__ pmask,
    const int* __restrict__ nmask,
    float* __restrict__ pos, float* __restrict__ neg, float* __restrict__ cnt) {
  __shared__ __hip_bfloat16 sim[128 * PADW];  // 34 KB -> 4 blocks/CU

  const int tid = threadIdx.x;
  const int lane = tid & 63;
  const int quad = lane >> 4;
  const int l16 = lane & 15;
  const int wx = (tid >> 6) & 1;
  const int wy = tid >> 7;

  const int I0g = blockIdx.y * 128;
  const int J0g = blockIdx.x * 128;
  const int I0 = I0g + wy * 64;
  const int J0 = J0g + wx * 64;

  // ---- Phase 1: GEMM ----
  f32x4 acc[4][4] = {};
#pragma unroll
  for (int kt = 0; kt < 4; ++kt) {
    const int ko = kt * 32 + quad * 8;
    bf16x8 aF[4], bF[4];
#pragma unroll
    for (int mt = 0; mt < 4; ++mt)
      aF[mt] = *(const bf16x8*)(fn + (size_t)(I0 + mt * 16 + l16) * DD + ko);
#pragma unroll
    for (int nt = 0; nt < 4; ++nt)
      bF[nt] = *(const bf16x8*)(fn + (size_t)(J0 + nt * 16 + l16) * DD + ko);
#pragma unroll
    for (int mt = 0; mt < 4; ++mt)
#pragma unroll
      for (int nt = 0; nt < 4; ++nt)
        acc[mt][nt] = __builtin_amdgcn_mfma_f32_16x16x32_bf16(
            bF[nt], aF[mt], acc[mt][nt], 0, 0, 0);  // SWAPPED operands
  }

  // ---- Phase 2: exp -> LDS (bf16) ----
  const float tinv = 1.0f / 0.07f;
#pragma unroll
  for (int mt = 0; mt < 4; ++mt) {
    const int iLoc = wy * 64 + mt * 16 + l16;
#pragma unroll
    for (int nt = 0; nt < 4; ++nt) {
      const int jLoc = wx * 64 + nt * 16 + quad * 4;
      ushort4 w;
      w.x = f2bf(__expf(acc[mt][nt][0] * tinv));
      w.y = f2bf(__expf(acc[mt][nt][1] * tinv));
      w.z = f2bf(__expf(acc[mt][nt][2] * tinv));
      w.w = f2bf(__expf(acc[mt][nt][3] * tinv));
      *(ushort4*)(sim + iLoc * PADW + jLoc) = w;  // 8B store, ~4-way conflict
    }
  }
  __syncthreads();

  // ---- Phase 3: row-major masked accumulation ----
  const int rGrp = tid >> 4;  // 16 rows per iteration
  const int cl = tid & 15;    // 16 col-groups x 8 cols = 128 cols
#pragma unroll
  for (int it = 0; it < 8; ++it) {
    const int rLoc = it * 16 + rGrp;
    const int iG = I0g + rLoc;
    const size_t mOff = (size_t)iG * NN + J0g + cl * 8;
    const int4 pa = *(const int4*)(pmask + mOff);
    const int4 pb = *(const int4*)(pmask + mOff + 4);
    const int4 na = *(const int4*)(nmask + mOff);
    const int4 nb = *(const int4*)(nmask + mOff + 4);
    const bf16x8 ev = *(const bf16x8*)(sim + rLoc * PADW + cl * 8);
    float p = 0.f, q = 0.f, c = 0.f;
#pragma unroll
    for (int r = 0; r < 8; ++r) {
      int pm = (r < 4) ? (&pa.x)[r] : (&pb.x)[r - 4];
      int nm = (r < 4) ? (&na.x)[r] : (&nb.x)[r - 4];
      const int jG = J0g + cl * 8 + r;
      if (iG == jG) { pm = 0; nm = 0; }  // zero self-contrast
      const float e = __uint_as_float(((unsigned int)(unsigned short)ev[r]) << 16);
      p = fmaf(e, (float)pm, p);
      q = fmaf(e, (float)nm, q);
      c += (float)pm;
    }
    // reduce over the 16 col-lanes (consecutive lane ids -> xor 1,2,4,8)
#pragma unroll
    for (int m = 1; m < 16; m <<= 1) {
      p += __shfl_xor(p, m, 64);
      q += __shfl_xor(q, m, 64);
      c += __shfl_xor(c, m, 64);
    }
    if (cl == 0) atomicAdd(&pos[iG], p);
    else if (cl == 1) atomicAdd(&neg[iG], q);
    else if (cl == 2) atomicAdd(&cnt[iG], c);
  }
}

// ---------------------------------------------------------------------------
// Kernel 3: loss = -mean(log(pos/(pos+neg)) / cnt)
// ---------------------------------------------------------------------------
__global__ __launch_bounds__(256) void finalize_kernel(
    const float* __restrict__ pos, const float* __restrict__ neg,
    const float* __restrict__ cnt, float* __restrict__ out) {
  float s = 0.f;
  for (int i = threadIdx.x; i < NN; i += 256) {
    const float p = pos[i];
    const float q = neg[i];
    s += logf(p / (p + q)) / cnt[i];
  }
#pragma unroll
  for (int m = 1; m < 64; m <<= 1) s += __shfl_xor(s, m, 64);
  __shared__ float wsum[4];
  if ((threadIdx.x & 63) == 0) wsum[threadIdx.x >> 6] = s;
  __syncthreads();
  if (threadIdx.x == 0) {
    out[0] = -(wsum[0] + wsum[1] + wsum[2] + wsum[3]) / (float)NN;
  }
}

extern "C" void kernel_launch(void* const* d_in, const int* in_sizes, int n_in,
                              void* d_out, int out_size, void* d_ws, size_t ws_size,
                              hipStream_t stream) {
  const float* features = (const float*)d_in[0];
  const int* pmask = (const int*)d_in[1];
  const int* nmask = (const int*)d_in[2];
  float* out = (float*)d_out;

  char* ws = (char*)d_ws;
  __hip_bfloat16* fn = (__hip_bfloat16*)ws;  // 2 MB
  float* pos = (float*)(ws + (size_t)NN * DD * sizeof(__hip_bfloat16));
  float* neg = pos + NN;
  float* cnt = neg + NN;

  hipMemsetAsync(pos, 0, 3 * (size_t)NN * sizeof(float), stream);
  normalize_kernel<<<NN / 4, 256, 0, stream>>>(features, fn);
  ssnt_main<<<dim3(NN / 128, NN / 128), 256, 0, stream>>>(fn, pmask, nmask,
                                                          pos, neg, cnt);
  finalize_kernel<<<1, 256, 0, stream>>>(pos, neg, cnt, out);
}